// Round 1
// baseline (523.704 us; speedup 1.0000x reference)
//
#include <hip/hip_runtime.h>
#include <cstdint>
#include <cstddef>

// ---- problem constants ----
#define BQ   8
#define NP   512
#define GQ   16
#define PP   528      // NP + GQ
#define RT   4224     // BQ * PP
#define CC   91
#define FEATD 12544
#define REPD 1024
#define NH   512      // padded head output cols (455 used: 91 cls + 364 box)
#define NHU  455
#define BETA (1.0f/9.0f)
#define WSC  64.0f    // fp8 weight pre-scale (exact pow2; undone in reduce/loss)

typedef float f32x4 __attribute__((ext_vector_type(4)));
typedef int   v8i  __attribute__((ext_vector_type(8)));
typedef float v16f __attribute__((ext_vector_type(16)));

__device__ __forceinline__ unsigned short f2bf(float f) {
  unsigned int x = __float_as_uint(f);
  unsigned int r = (x + 0x7fffu + ((x >> 16) & 1u)) >> 16;
  return (unsigned short)r;
}
__device__ __forceinline__ float bf2f(unsigned short u) {
  return __uint_as_float((unsigned int)u << 16);
}
__device__ __forceinline__ unsigned char f2fp8(float f) {
  return (unsigned char)(__builtin_amdgcn_cvt_pk_fp8_f32(f, 0.0f, 0, false) & 0xff);
}

// async global->LDS DMA, 16 B per lane; HW writes lane L to base + L*16.
__device__ __forceinline__ void ld_lds16(const void* g, void* l) {
  __builtin_amdgcn_global_load_lds(
      (const __attribute__((address_space(1))) void*)g,
      (__attribute__((address_space(3))) void*)l, 16, 0, 0);
}

// ---- workspace layout (bytes); total ~107 MB (ws >= 230.6 MB proven R2) ----
constexpr size_t O_W1T = 0;
constexpr size_t SZ_W1T = (size_t)FEATD * REPD;             // W1^T fp8 [1024][12544]
constexpr size_t O_W2T = O_W1T + SZ_W1T;
constexpr size_t SZ_W2T = (size_t)REPD * REPD;              // W2^T fp8
constexpr size_t O_WH  = O_W2T + SZ_W2T;
constexpr size_t SZ_WH = (size_t)NH * REPD;                 // [Wcls|Wbox]^T fp8
constexpr size_t O_BH  = O_WH + SZ_WH;
constexpr size_t SZ_BH = (size_t)NH * 4;
constexpr size_t O_X1  = O_BH + SZ_BH;
constexpr size_t SZ_X1 = (size_t)RT * REPD;                 // x1 fp8
constexpr size_t O_X2  = O_X1 + SZ_X1;                      // x2 fp8
constexpr size_t O_LAB = O_X2 + SZ_X1;
constexpr size_t O_TGT = O_LAB + (size_t)RT * 4;
constexpr size_t O_NLL = O_TGT + (size_t)RT * 16;
constexpr size_t O_VC  = O_NLL + (size_t)RT * 4;
constexpr size_t O_SL1 = O_VC + (size_t)RT * 4;
constexpr size_t O_PART = ((O_SL1 + (size_t)RT * 4) + 255) & ~(size_t)255;
constexpr size_t SZ_PART = (size_t)4 * RT * REPD * 2;       // bf16 partials, 34.6 MB max
constexpr size_t O_F8 = O_PART + SZ_PART;                   // fp8 features, 53 MB

// ---- prep: feature fp8-convert + weight transpose-convert(x64) + head + matcher ----
__device__ __forceinline__ void t32(const float* __restrict__ in, unsigned char* __restrict__ out,
                                    int K, int N, int row_off, int out_ld,
                                    int bx, int by, int t, float (*tile)[33]) {
  int tx = t & 31, ty = t >> 5;
  int n0 = bx * 32, k0 = by * 32;
#pragma unroll
  for (int i = 0; i < 4; ++i) {
    int k = k0 + ty + i * 8, n = n0 + tx;
    if (k < K && n < N) tile[ty + i * 8][tx] = in[(size_t)k * N + n];
  }
  __syncthreads();
#pragma unroll
  for (int i = 0; i < 4; ++i) {
    int n = n0 + ty + i * 8, k = k0 + tx;
    if (n < N && k < K) out[(size_t)(n + row_off) * out_ld + k] = f2fp8(tile[tx][ty + i * 8] * WSC);
  }
}

#define NB_CV ((RT * FEATD / 4) / 256)   // 51744
#define NB_W1 ((REPD/32)*(FEATD/32))     // 12544
#define NB_W2 ((REPD/32)*(REPD/32))      // 1024
#define NB_WC (3*(REPD/32))              // 96
#define NB_WB (12*(REPD/32))             // 384
#define NB_HI 230
#define NB_MT 17
#define NB_PREP (NB_CV+NB_W1+NB_W2+NB_WC+NB_WB+NB_HI+NB_MT)

__global__ void prep(const float* __restrict__ feat, unsigned int* __restrict__ feat8,
                     const float* __restrict__ W1, const float* __restrict__ W2,
                     const float* __restrict__ Wcls, const float* __restrict__ Wbox,
                     const float* __restrict__ bcls, const float* __restrict__ bbox,
                     const float* __restrict__ proposals, const float* __restrict__ gt_boxes,
                     const int* __restrict__ gt_labels,
                     unsigned char* __restrict__ W1t, unsigned char* __restrict__ W2t,
                     unsigned char* __restrict__ Wh, float* __restrict__ bh,
                     int* __restrict__ labels, float* __restrict__ tgts) {
  __shared__ float tile[32][33];
  int b = blockIdx.x, t = threadIdx.x;
  if (b < NB_CV) {
    long i = (long)b * 256 + t;
    float4 f = ((const float4*)feat)[i];
    unsigned int r = (unsigned int)__builtin_amdgcn_cvt_pk_fp8_f32(f.x, f.y, 0, false);
    r = (unsigned int)__builtin_amdgcn_cvt_pk_fp8_f32(f.z, f.w, (int)r, true);
    feat8[i] = r;
    return;
  }
  b -= NB_CV;
  if (b < NB_W1) { t32(W1, W1t, FEATD, REPD, 0, FEATD, b % (REPD/32), b / (REPD/32), t, tile); return; }
  b -= NB_W1;
  if (b < NB_W2) { t32(W2, W2t, REPD, REPD, 0, REPD, b % 32, b / 32, t, tile); return; }
  b -= NB_W2;
  if (b < NB_WC) { t32(Wcls, Wh, REPD, CC, 0, REPD, b % 3, b / 3, t, tile); return; }
  b -= NB_WC;
  if (b < NB_WB) { t32(Wbox, Wh, REPD, 4 * CC, CC, REPD, b % 12, b / 12, t, tile); return; }
  b -= NB_WB;
  if (b < NB_HI) {
    int idx = b * 256 + t;
    const int npad = (NH - NHU) * REPD;   // 58368 bytes of fp8 zero
    if (idx < npad) Wh[(size_t)NHU * REPD + idx] = 0;
    else {
      int i2 = idx - npad;
      if (i2 < NH) bh[i2] = (i2 < CC) ? bcls[i2] : (i2 < NHU ? bbox[i2 - CC] : 0.0f);
    }
    return;
  }
  b -= NB_HI;
  // ---- matcher + encode (exact fp32) ----
  int r = b * 256 + t;
  if (r >= RT) return;
  int bi_ = r / PP, p = r % PP;
  float x0, y0, x1, y1;
  if (p < NP) {
    const float* qq = proposals + ((size_t)bi_ * NP + p) * 4;
    x0 = qq[0]; y0 = qq[1]; x1 = qq[2]; y1 = qq[3];
  } else {
    const float* qq = gt_boxes + ((size_t)bi_ * GQ + (p - NP)) * 4;
    x0 = qq[0]; y0 = qq[1]; x1 = qq[2]; y1 = qq[3];
  }
  float ap = (x1 - x0) * (y1 - y0);
  float best = -1.0f; int bg = 0;
#pragma unroll
  for (int g = 0; g < GQ; ++g) {
    const float* gb = gt_boxes + ((size_t)bi_ * GQ + g) * 4;
    float gx0 = gb[0], gy0 = gb[1], gx1 = gb[2], gy1 = gb[3];
    float ag = (gx1 - gx0) * (gy1 - gy0);
    float iw = fmaxf(fminf(gx1, x1) - fmaxf(gx0, x0), 0.0f);
    float ih = fmaxf(fminf(gy1, y1) - fmaxf(gy0, y0), 0.0f);
    float inter = iw * ih;
    float iou = inter / (ag + ap - inter);
    if (iou > best) { best = iou; bg = g; }   // strict > keeps first max (jnp.argmax)
  }
  int lab = gt_labels[bi_ * GQ + bg];
  if (best < 0.5f) lab = 0;    // FG==BG==0.5 -> ignore band empty
  labels[r] = lab;
  const float* gb = gt_boxes + ((size_t)bi_ * GQ + bg) * 4;
  float ew = x1 - x0, eh = y1 - y0;
  float ex = x0 + 0.5f * ew, ey = y0 + 0.5f * eh;
  float gw = gb[2] - gb[0], gh = gb[3] - gb[1];
  float gx = gb[0] + 0.5f * gw, gy = gb[1] + 0.5f * gh;
  tgts[r * 4 + 0] = 10.0f * (gx - ex) / ew;
  tgts[r * 4 + 1] = 10.0f * (gy - ey) / eh;
  tgts[r * 4 + 2] = 5.0f * logf(gw / ew);
  tgts[r * 4 + 3] = 5.0f * logf(gh / eh);
}

// ---- MX-scaled fp8 MFMA GEMM: 128x128 tile, BK=64, single-buffer 2-barrier ----
// Same proven skeleton as R2 (XCD pair-mapping, 4 blocks/CU), but the inner math
// is v_mfma_f32_32x32x64_f8f6f4 with unit E8M0 scales (127 = 2^0): bit-identical
// fp8 products at 2x the MFMA rate (learn_hip m148: 995 -> 1628 TF on this
// exact structure). Wave computes 64x64 as 2x2 of 32x32; acc = 64 VGPR (same).
// LDS placement: per 1 KB window (16 rows x 64 B), global chunk (r, c) lands at
// slot c*16+r (column-major), so the scaled A-frag (32 consecutive K-bytes:
// row=l&31, k=(l>>5)*32+e) is two ds_read_b128 at +c*256 + r*16 -- each 16-lane
// quarter spreads over all 8 bank-quads (2-way aliasing = free, b128 floor).
__global__ __launch_bounds__(256, 4)
void gemm_f8(const unsigned char* __restrict__ A, const unsigned char* __restrict__ Bt,
             unsigned short* __restrict__ P, int M, int Nc, int K, int Kspl,
             int n_nblk, int n_my, int npairs) {
  __shared__ unsigned char As[128 * 64];
  __shared__ unsigned char Bs[128 * 64];

  const int g = blockIdx.x;
  const int xcd = g & 7;
  const int kix = g >> 3;
  const int n  = kix % n_nblk;
  const int pi = kix / n_nblk;
  const int p  = pi * 8 + xcd;
  if (p >= npairs) return;                 // uniform dummy exit, before any barrier
  const int y  = p % n_my;
  const int kz = p / n_my;
  const int m0 = y * 128, n0 = n * 128;

  const int tid = threadIdx.x;
  const int w = tid >> 6, L = tid & 63;
  const int l31 = L & 31, h = L >> 5;
  const int wr = (w >> 1) * 64, wc = (w & 1) * 64;
  const size_t kbase = (size_t)kz * Kspl;

  // staging: window = 16 rows x 64 B (1 KB / wave-instr); lane L fetches
  // global (row = L&15, chunk = L>>4) -> lands at LDS slot c*16+r.
  const int srow = L & 15, schk = (L >> 4) * 16;
  const int sg = 2 * w;                    // wave w owns windows {2w, 2w+1}
  const unsigned char* gA0 = A  + (size_t)(m0 + sg * 16 + srow) * K + kbase + schk;
  const unsigned char* gA1 = A  + (size_t)(m0 + (sg + 1) * 16 + srow) * K + kbase + schk;
  const unsigned char* gB0 = Bt + (size_t)(n0 + sg * 16 + srow) * K + kbase + schk;
  const unsigned char* gB1 = Bt + (size_t)(n0 + (sg + 1) * 16 + srow) * K + kbase + schk;
  unsigned char* lA0 = &As[sg * 1024];
  unsigned char* lA1 = &As[(sg + 1) * 1024];
  unsigned char* lB0 = &Bs[sg * 1024];
  unsigned char* lB1 = &Bs[(sg + 1) * 1024];

  // fragment byte addresses: row rho -> (rho>>4)*1024 + (rho&15)*16 + h*512 (+j*256)
  int ab[2], bb[2];
#pragma unroll
  for (int i = 0; i < 2; ++i) {
    int ra = wr + i * 32 + l31;
    ab[i] = (ra >> 4) * 1024 + (ra & 15) * 16 + h * 512;
    int rb = wc + i * 32 + l31;
    bb[i] = (rb >> 4) * 1024 + (rb & 15) * 16 + h * 512;
  }

  v16f acc[2][2] = {};
  const int nk = Kspl >> 6;
  for (int kb = 0; kb < nk; ++kb) {
    const int ko = kb * 64;
    ld_lds16(gA0 + ko, lA0);
    ld_lds16(gA1 + ko, lA1);
    ld_lds16(gB0 + ko, lB0);
    ld_lds16(gB1 + ko, lB1);
    __syncthreads();   // vmcnt drain + barrier: tile staged
    v8i a[2], b[2];
#pragma unroll
    for (int i = 0; i < 2; ++i) {
      int4 alo = *(const int4*)&As[ab[i]];
      int4 ahi = *(const int4*)&As[ab[i] + 256];
      a[i] = (v8i){alo.x, alo.y, alo.z, alo.w, ahi.x, ahi.y, ahi.z, ahi.w};
      int4 blo = *(const int4*)&Bs[bb[i]];
      int4 bhi = *(const int4*)&Bs[bb[i] + 256];
      b[i] = (v8i){blo.x, blo.y, blo.z, blo.w, bhi.x, bhi.y, bhi.z, bhi.w};
    }
#pragma unroll
    for (int i = 0; i < 2; ++i)
#pragma unroll
      for (int j = 0; j < 2; ++j)
        acc[i][j] = __builtin_amdgcn_mfma_scale_f32_32x32x64_f8f6f4(
            a[i], b[j], acc[i][j], 0, 0, 0, 127, 0, 127);   // fmtA=fmtB=FP8, scales=2^0
    __syncthreads();   // protect LDS from next iteration's DMA
  }

  // epilogue: 32x32 C/D layout col=l&31, row=(reg&3)+8*(reg>>2)+4*(l>>5) -> bf16
  unsigned short* Pz = P + (size_t)kz * M * Nc;
#pragma unroll
  for (int i = 0; i < 2; ++i) {
#pragma unroll
    for (int j = 0; j < 2; ++j) {
      int colb = n0 + wc + j * 32 + l31;
#pragma unroll
      for (int r = 0; r < 16; ++r) {
        int row = m0 + wr + i * 32 + (r & 3) + 8 * (r >> 2) + 4 * h;
        Pz[(size_t)row * Nc + colb] = f2bf(acc[i][j][r]);
      }
    }
  }
}

// ---- split-K reduce (bf16 partials) + 1/WSC + bias + ReLU -> fp8 out ----
template <int S>
__global__ void reduce_fp8k(const unsigned short* __restrict__ P, const float* __restrict__ bias,
                            unsigned int* __restrict__ outp, long MN4, int nc4) {
  long i = (long)blockIdx.x * blockDim.x + threadIdx.x;
  long stride = (long)gridDim.x * blockDim.x;
  const ushort4* P4 = (const ushort4*)P;
  const float4* B4 = (const float4*)bias;
  for (; i < MN4; i += stride) {
    float vx = 0, vy = 0, vz = 0, vw = 0;
#pragma unroll
    for (int s = 0; s < S; ++s) {
      ushort4 u = P4[s * MN4 + i];
      vx += bf2f(u.x); vy += bf2f(u.y); vz += bf2f(u.z); vw += bf2f(u.w);
    }
    float4 b = B4[i % nc4];
    vx = fmaxf(vx * (1.0f / WSC) + b.x, 0.0f);
    vy = fmaxf(vy * (1.0f / WSC) + b.y, 0.0f);
    vz = fmaxf(vz * (1.0f / WSC) + b.z, 0.0f);
    vw = fmaxf(vw * (1.0f / WSC) + b.w, 0.0f);
    unsigned int r = (unsigned int)__builtin_amdgcn_cvt_pk_fp8_f32(vx, vy, 0, false);
    r = (unsigned int)__builtin_amdgcn_cvt_pk_fp8_f32(vz, vw, (int)r, true);
    outp[i] = r;
  }
}

// ---- per-row loss, reading GEMM3's 4 bf16 split-K slices + bias directly ----
__global__ void loss_row(const unsigned short* __restrict__ P, const float* __restrict__ bh,
                         const int* __restrict__ labels, const float* __restrict__ tgts,
                         float* __restrict__ nll_v, float* __restrict__ vc_v,
                         float* __restrict__ sl1_v) {
  int r = blockIdx.x;
  int l = threadIdx.x;
  const size_t SL = (size_t)RT * NH;
  const unsigned short* p0 = P + (size_t)r * NH;
#define COLV(c) ((bf2f(p0[(c)]) + bf2f(p0[SL + (c)]) + bf2f(p0[2 * SL + (c)]) + \
                  bf2f(p0[3 * SL + (c)])) * (1.0f / WSC) + bh[(c)])
  float v1 = COLV(l);
  float v2 = (l < CC - 64) ? COLV(64 + l) : -3.4e38f;
  float m = fmaxf(v1, v2);
#pragma unroll
  for (int o = 32; o; o >>= 1) m = fmaxf(m, __shfl_xor(m, o));
  float e = __expf(v1 - m) + ((l < CC - 64) ? __expf(v2 - m) : 0.0f);
#pragma unroll
  for (int o = 32; o; o >>= 1) e += __shfl_xor(e, o);
  if (l == 0) {
    float lse = m + __logf(e);
    int lab = labels[r];
    int sl = lab < 0 ? 0 : (lab > CC - 1 ? CC - 1 : lab);
    float valid = (lab >= 0) ? 1.0f : 0.0f;
    nll_v[r] = (lse - COLV(sl)) * valid;
    vc_v[r] = valid;
    float s = 0.0f;
#pragma unroll
    for (int d = 0; d < 4; ++d) {
      float pd = COLV(CC + sl * 4 + d);
      float ad = fabsf(pd - tgts[r * 4 + d]);
      s += (ad < BETA) ? 0.5f * ad * ad / BETA : ad - 0.5f * BETA;
    }
    sl1_v[r] = (lab > 0) ? s : 0.0f;
  }
#undef COLV
}

// ---- deterministic final reduce ----
__global__ void reduce_final(const float* __restrict__ nll_v, const float* __restrict__ vc_v,
                             const float* __restrict__ sl1_v, float* __restrict__ out) {
  __shared__ float s1[256], s2[256], s3[256];
  int t = threadIdx.x;
  float a = 0, b = 0, c = 0;
  for (int i = t; i < RT; i += 256) { a += nll_v[i]; b += vc_v[i]; c += sl1_v[i]; }
  s1[t] = a; s2[t] = b; s3[t] = c;
  __syncthreads();
  for (int o = 128; o; o >>= 1) {
    if (t < o) { s1[t] += s1[t + o]; s2[t] += s2[t + o]; s3[t] += s3[t + o]; }
    __syncthreads();
  }
  if (t == 0) {
    out[0] = s1[0] / fmaxf(s2[0], 1.0f);
    out[1] = s3[0] / (float)RT;
  }
}

extern "C" void kernel_launch(void* const* d_in, const int* in_sizes, int n_in,
                              void* d_out, int out_size, void* d_ws, size_t ws_size,
                              hipStream_t stream) {
  const float* proposals = (const float*)d_in[0];
  const float* gt_boxes  = (const float*)d_in[1];
  const float* features  = (const float*)d_in[2];
  const float* W1   = (const float*)d_in[3];
  const float* b1   = (const float*)d_in[4];
  const float* W2   = (const float*)d_in[5];
  const float* b2   = (const float*)d_in[6];
  const float* Wcls = (const float*)d_in[7];
  const float* bcls = (const float*)d_in[8];
  const float* Wbox = (const float*)d_in[9];
  const float* bbox = (const float*)d_in[10];
  const int* gt_labels = (const int*)d_in[11];
  float* out = (float*)d_out;

  char* ws = (char*)d_ws;
  unsigned char* W1t = (unsigned char*)(ws + O_W1T);
  unsigned char* W2t = (unsigned char*)(ws + O_W2T);
  unsigned char* Wh  = (unsigned char*)(ws + O_WH);
  float* bh          = (float*)(ws + O_BH);
  unsigned char* x1  = (unsigned char*)(ws + O_X1);
  unsigned char* x2  = (unsigned char*)(ws + O_X2);
  int* labels        = (int*)(ws + O_LAB);
  float* tgts        = (float*)(ws + O_TGT);
  float* nll_v       = (float*)(ws + O_NLL);
  float* vc_v        = (float*)(ws + O_VC);
  float* sl1_v       = (float*)(ws + O_SL1);
  unsigned short* part = (unsigned short*)(ws + O_PART);
  unsigned char* feat8 = (unsigned char*)(ws + O_F8);

  // 1. prep: feature fp8 convert + weight transpose-convert(x64) + head + matcher
  prep<<<NB_PREP, 256, 0, stream>>>(features, (unsigned int*)feat8, W1, W2, Wcls, Wbox,
                                    bcls, bbox, proposals, gt_boxes, gt_labels,
                                    W1t, W2t, Wh, bh, labels, tgts);

  // 2. GEMM1: split-4, pairs=(y,kz)=132, 8 n-blocks -> grid 8*8*17=1088
  gemm_f8<<<1088, 256, 0, stream>>>(feat8, W1t, part, RT, REPD, FEATD, FEATD / 4,
                                    8, 33, 132);
  reduce_fp8k<4><<<2048, 256, 0, stream>>>(part, b1, (unsigned int*)x1,
                                           (long)RT * REPD / 4, REPD / 4);

  // 3. GEMM2: split-2, pairs=66 -> grid 8*8*9=576
  gemm_f8<<<576, 256, 0, stream>>>(x1, W2t, part, RT, REPD, REPD, REPD / 2,
                                   8, 33, 66);
  reduce_fp8k<2><<<2048, 256, 0, stream>>>(part, b2, (unsigned int*)x2,
                                           (long)RT * REPD / 4, REPD / 4);

  // 4. GEMM3: split-4, Nc=512 (4 n-blocks), pairs=132 -> grid 8*4*17=544
  gemm_f8<<<544, 256, 0, stream>>>(x2, Wh, part, RT, NH, REPD, REPD / 4,
                                   4, 33, 132);

  // 5. losses (loss_row folds GEMM3's 4-slice reduce + bias + 1/WSC)
  loss_row<<<RT, 64, 0, stream>>>(part, bh, labels, tgts, nll_v, vc_v, sl1_v);
  reduce_final<<<1, 256, 0, stream>>>(nll_v, vc_v, sl1_v, out);
}

// Round 2
// 521.920 us; speedup vs baseline: 1.0034x; 1.0034x over previous
//
#include <hip/hip_runtime.h>
#include <cstdint>
#include <cstddef>

// ---- problem constants ----
#define BQ   8
#define NP   512
#define GQ   16
#define PP   528      // NP + GQ
#define RT   4224     // BQ * PP
#define CC   91
#define FEATD 12544
#define REPD 1024
#define NH   512      // padded head output cols (455 used: 91 cls + 364 box)
#define NHU  455
#define BETA (1.0f/9.0f)
#define WSC  64.0f    // fp8 weight pre-scale (exact pow2; undone in reduce/loss)

typedef float f32x4 __attribute__((ext_vector_type(4)));
typedef int   v8i  __attribute__((ext_vector_type(8)));
typedef float v16f __attribute__((ext_vector_type(16)));

__device__ __forceinline__ unsigned short f2bf(float f) {
  unsigned int x = __float_as_uint(f);
  unsigned int r = (x + 0x7fffu + ((x >> 16) & 1u)) >> 16;
  return (unsigned short)r;
}
__device__ __forceinline__ float bf2f(unsigned short u) {
  return __uint_as_float((unsigned int)u << 16);
}
__device__ __forceinline__ unsigned char f2fp8(float f) {
  return (unsigned char)(__builtin_amdgcn_cvt_pk_fp8_f32(f, 0.0f, 0, false) & 0xff);
}

// async global->LDS DMA, 16 B per lane; HW writes lane L to base + L*16.
__device__ __forceinline__ void ld_lds16(const void* g, void* l) {
  __builtin_amdgcn_global_load_lds(
      (const __attribute__((address_space(1))) void*)g,
      (__attribute__((address_space(3))) void*)l, 16, 0, 0);
}

// ---- workspace layout (bytes); total ~107 MB (ws >= 230.6 MB proven R2) ----
constexpr size_t O_W1T = 0;
constexpr size_t SZ_W1T = (size_t)FEATD * REPD;             // W1^T fp8 [1024][12544]
constexpr size_t O_W2T = O_W1T + SZ_W1T;
constexpr size_t SZ_W2T = (size_t)REPD * REPD;              // W2^T fp8
constexpr size_t O_WH  = O_W2T + SZ_W2T;
constexpr size_t SZ_WH = (size_t)NH * REPD;                 // [Wcls|Wbox]^T fp8
constexpr size_t O_BH  = O_WH + SZ_WH;
constexpr size_t SZ_BH = (size_t)NH * 4;
constexpr size_t O_X1  = O_BH + SZ_BH;
constexpr size_t SZ_X1 = (size_t)RT * REPD;                 // x1 fp8
constexpr size_t O_X2  = O_X1 + SZ_X1;                      // x2 fp8
constexpr size_t O_LAB = O_X2 + SZ_X1;
constexpr size_t O_TGT = O_LAB + (size_t)RT * 4;
constexpr size_t O_NLL = O_TGT + (size_t)RT * 16;
constexpr size_t O_VC  = O_NLL + (size_t)RT * 4;
constexpr size_t O_SL1 = O_VC + (size_t)RT * 4;
constexpr size_t O_PART = ((O_SL1 + (size_t)RT * 4) + 255) & ~(size_t)255;
constexpr size_t SZ_PART = (size_t)4 * RT * REPD * 2;       // bf16 partials, 34.6 MB max
constexpr size_t O_F8 = O_PART + SZ_PART;                   // fp8 features, 53 MB

// ---- prep: feature fp8-convert + weight transpose-convert(x64) + head + matcher ----
__device__ __forceinline__ void t32(const float* __restrict__ in, unsigned char* __restrict__ out,
                                    int K, int N, int row_off, int out_ld,
                                    int bx, int by, int t, float (*tile)[33]) {
  int tx = t & 31, ty = t >> 5;
  int n0 = bx * 32, k0 = by * 32;
#pragma unroll
  for (int i = 0; i < 4; ++i) {
    int k = k0 + ty + i * 8, n = n0 + tx;
    if (k < K && n < N) tile[ty + i * 8][tx] = in[(size_t)k * N + n];
  }
  __syncthreads();
#pragma unroll
  for (int i = 0; i < 4; ++i) {
    int n = n0 + ty + i * 8, k = k0 + tx;
    if (n < N && k < K) out[(size_t)(n + row_off) * out_ld + k] = f2fp8(tile[tx][ty + i * 8] * WSC);
  }
}

#define NB_CV ((RT * FEATD / 4) / 256)   // 51744
#define NB_W1 ((REPD/32)*(FEATD/32))     // 12544
#define NB_W2 ((REPD/32)*(REPD/32))      // 1024
#define NB_WC (3*(REPD/32))              // 96
#define NB_WB (12*(REPD/32))             // 384
#define NB_HI 230
#define NB_MT 17
#define NB_PREP (NB_CV+NB_W1+NB_W2+NB_WC+NB_WB+NB_HI+NB_MT)

__global__ void prep(const float* __restrict__ feat, unsigned int* __restrict__ feat8,
                     const float* __restrict__ W1, const float* __restrict__ W2,
                     const float* __restrict__ Wcls, const float* __restrict__ Wbox,
                     const float* __restrict__ bcls, const float* __restrict__ bbox,
                     const float* __restrict__ proposals, const float* __restrict__ gt_boxes,
                     const int* __restrict__ gt_labels,
                     unsigned char* __restrict__ W1t, unsigned char* __restrict__ W2t,
                     unsigned char* __restrict__ Wh, float* __restrict__ bh,
                     int* __restrict__ labels, float* __restrict__ tgts) {
  __shared__ float tile[32][33];
  int b = blockIdx.x, t = threadIdx.x;
  if (b < NB_CV) {
    long i = (long)b * 256 + t;
    float4 f = ((const float4*)feat)[i];
    unsigned int r = (unsigned int)__builtin_amdgcn_cvt_pk_fp8_f32(f.x, f.y, 0, false);
    r = (unsigned int)__builtin_amdgcn_cvt_pk_fp8_f32(f.z, f.w, (int)r, true);
    feat8[i] = r;
    return;
  }
  b -= NB_CV;
  if (b < NB_W1) { t32(W1, W1t, FEATD, REPD, 0, FEATD, b % (REPD/32), b / (REPD/32), t, tile); return; }
  b -= NB_W1;
  if (b < NB_W2) { t32(W2, W2t, REPD, REPD, 0, REPD, b % 32, b / 32, t, tile); return; }
  b -= NB_W2;
  if (b < NB_WC) { t32(Wcls, Wh, REPD, CC, 0, REPD, b % 3, b / 3, t, tile); return; }
  b -= NB_WC;
  if (b < NB_WB) { t32(Wbox, Wh, REPD, 4 * CC, CC, REPD, b % 12, b / 12, t, tile); return; }
  b -= NB_WB;
  if (b < NB_HI) {
    int idx = b * 256 + t;
    const int npad = (NH - NHU) * REPD;   // 58368 bytes of fp8 zero
    if (idx < npad) Wh[(size_t)NHU * REPD + idx] = 0;
    else {
      int i2 = idx - npad;
      if (i2 < NH) bh[i2] = (i2 < CC) ? bcls[i2] : (i2 < NHU ? bbox[i2 - CC] : 0.0f);
    }
    return;
  }
  b -= NB_HI;
  // ---- matcher + encode (exact fp32) ----
  int r = b * 256 + t;
  if (r >= RT) return;
  int bi_ = r / PP, p = r % PP;
  float x0, y0, x1, y1;
  if (p < NP) {
    const float* qq = proposals + ((size_t)bi_ * NP + p) * 4;
    x0 = qq[0]; y0 = qq[1]; x1 = qq[2]; y1 = qq[3];
  } else {
    const float* qq = gt_boxes + ((size_t)bi_ * GQ + (p - NP)) * 4;
    x0 = qq[0]; y0 = qq[1]; x1 = qq[2]; y1 = qq[3];
  }
  float ap = (x1 - x0) * (y1 - y0);
  float best = -1.0f; int bg = 0;
#pragma unroll
  for (int g = 0; g < GQ; ++g) {
    const float* gb = gt_boxes + ((size_t)bi_ * GQ + g) * 4;
    float gx0 = gb[0], gy0 = gb[1], gx1 = gb[2], gy1 = gb[3];
    float ag = (gx1 - gx0) * (gy1 - gy0);
    float iw = fmaxf(fminf(gx1, x1) - fmaxf(gx0, x0), 0.0f);
    float ih = fmaxf(fminf(gy1, y1) - fmaxf(gy0, y0), 0.0f);
    float inter = iw * ih;
    float iou = inter / (ag + ap - inter);
    if (iou > best) { best = iou; bg = g; }   // strict > keeps first max (jnp.argmax)
  }
  int lab = gt_labels[bi_ * GQ + bg];
  if (best < 0.5f) lab = 0;    // FG==BG==0.5 -> ignore band empty
  labels[r] = lab;
  const float* gb = gt_boxes + ((size_t)bi_ * GQ + bg) * 4;
  float ew = x1 - x0, eh = y1 - y0;
  float ex = x0 + 0.5f * ew, ey = y0 + 0.5f * eh;
  float gw = gb[2] - gb[0], gh = gb[3] - gb[1];
  float gx = gb[0] + 0.5f * gw, gy = gb[1] + 0.5f * gh;
  tgts[r * 4 + 0] = 10.0f * (gx - ex) / ew;
  tgts[r * 4 + 1] = 10.0f * (gy - ey) / eh;
  tgts[r * 4 + 2] = 5.0f * logf(gw / ew);
  tgts[r * 4 + 3] = 5.0f * logf(gh / eh);
}

// ---- MX-scaled fp8 MFMA GEMM: 128x128 tile, BK=64, DOUBLE-BUFFERED pipeline ----
// R1 post-mortem: single-buffer 2-barrier exposed full HBM latency per K-step
// (MfmaUtil 15%, VALUBusy 6%, HBM 11% -- latency-bound). This version applies
// the proven minimum-2-phase recipe (T3/T4-lite, m201-verified combination):
//   prologue: STAGE(buf0)
//   loop:     STAGE(buf^1, t+1); vmcnt(4); barrier; ds_read+MFMA(buf); barrier
// The counted vmcnt(4) leaves tile t+1's 4 DMA loads in flight across both
// barriers -- HBM latency hides under compute + the other 3 resident blocks.
// Buffer select = runtime BYTE OFFSET (cur<<13), never a runtime-indexed
// pointer array (rule #20). sched_barrier(0) after asm waitcnt (rule #18).
// Math: v_mfma_f32_32x32x64_f8f6f4, unit E8M0 scales (127=2^0) -> bit-identical
// fp8 products at 2x issue rate. LDS 2 x 16 KB = 32 KB -> still 4 blocks/CU.
__global__ __launch_bounds__(256, 4)
void gemm_f8(const unsigned char* __restrict__ A, const unsigned char* __restrict__ Bt,
             unsigned short* __restrict__ P, int M, int Nc, int K, int Kspl,
             int n_nblk, int n_my, int npairs) {
  __shared__ unsigned char As[2 * 8192];
  __shared__ unsigned char Bs[2 * 8192];

  const int g = blockIdx.x;
  const int xcd = g & 7;
  const int kix = g >> 3;
  const int n  = kix % n_nblk;
  const int pi = kix / n_nblk;
  const int p  = pi * 8 + xcd;
  if (p >= npairs) return;                 // uniform dummy exit, before any barrier
  const int y  = p % n_my;
  const int kz = p / n_my;
  const int m0 = y * 128, n0 = n * 128;

  const int tid = threadIdx.x;
  const int w = tid >> 6, L = tid & 63;
  const int l31 = L & 31, h = L >> 5;
  const int wr = (w >> 1) * 64, wc = (w & 1) * 64;
  const size_t kbase = (size_t)kz * Kspl;

  // staging: window = 16 rows x 64 B (1 KB / wave-instr); lane L fetches
  // global (row = L&15, chunk = L>>4) -> lands at LDS slot c*16+r.
  const int srow = L & 15, schk = (L >> 4) * 16;
  const int sg = 2 * w;                    // wave w owns windows {2w, 2w+1}
  const int sgo0 = sg * 1024, sgo1 = (sg + 1) * 1024;
  const unsigned char* gA0 = A  + (size_t)(m0 + sg * 16 + srow) * K + kbase + schk;
  const unsigned char* gA1 = A  + (size_t)(m0 + (sg + 1) * 16 + srow) * K + kbase + schk;
  const unsigned char* gB0 = Bt + (size_t)(n0 + sg * 16 + srow) * K + kbase + schk;
  const unsigned char* gB1 = Bt + (size_t)(n0 + (sg + 1) * 16 + srow) * K + kbase + schk;

  // fragment byte addresses: row rho -> (rho>>4)*1024 + (rho&15)*16 + h*512 (+j*256)
  int ab[2], bb[2];
#pragma unroll
  for (int i = 0; i < 2; ++i) {
    int ra = wr + i * 32 + l31;
    ab[i] = (ra >> 4) * 1024 + (ra & 15) * 16 + h * 512;
    int rb = wc + i * 32 + l31;
    bb[i] = (rb >> 4) * 1024 + (rb & 15) * 16 + h * 512;
  }

  // prologue: stage tile 0 into buffer 0 (4 loads in flight)
  ld_lds16(gA0, &As[sgo0]);
  ld_lds16(gA1, &As[sgo1]);
  ld_lds16(gB0, &Bs[sgo0]);
  ld_lds16(gB1, &Bs[sgo1]);

  v16f acc[2][2] = {};
  const int nk = Kspl >> 6;
  int cur = 0;
  for (int kb = 0; kb < nk; ++kb) {
    const int cb = cur << 13;          // current buffer byte offset
    const int nb = cb ^ 8192;          // prefetch buffer byte offset
    if (kb + 1 < nk) {
      const int ko = (kb + 1) * 64;    // issue next tile's DMA (stays in flight)
      ld_lds16(gA0 + ko, &As[nb + sgo0]);
      ld_lds16(gA1 + ko, &As[nb + sgo1]);
      ld_lds16(gB0 + ko, &Bs[nb + sgo0]);
      ld_lds16(gB1 + ko, &Bs[nb + sgo1]);
      asm volatile("s_waitcnt vmcnt(4)" ::: "memory");   // tile kb's loads done
    } else {
      asm volatile("s_waitcnt vmcnt(0)" ::: "memory");   // last tile: drain
    }
    __builtin_amdgcn_sched_barrier(0);
    __builtin_amdgcn_s_barrier();      // all waves' tile-kb segments staged

    v8i a[2], b[2];
#pragma unroll
    for (int i = 0; i < 2; ++i) {
      int4 alo = *(const int4*)&As[cb + ab[i]];
      int4 ahi = *(const int4*)&As[cb + ab[i] + 256];
      a[i] = (v8i){alo.x, alo.y, alo.z, alo.w, ahi.x, ahi.y, ahi.z, ahi.w};
      int4 blo = *(const int4*)&Bs[cb + bb[i]];
      int4 bhi = *(const int4*)&Bs[cb + bb[i] + 256];
      b[i] = (v8i){blo.x, blo.y, blo.z, blo.w, bhi.x, bhi.y, bhi.z, bhi.w};
    }
#pragma unroll
    for (int i = 0; i < 2; ++i)
#pragma unroll
      for (int j = 0; j < 2; ++j)
        acc[i][j] = __builtin_amdgcn_mfma_scale_f32_32x32x64_f8f6f4(
            a[i], b[j], acc[i][j], 0, 0, 0, 127, 0, 127);   // fmtA=fmtB=FP8, 2^0

    asm volatile("s_waitcnt lgkmcnt(0)" ::: "memory");  // wave done reading cb
    __builtin_amdgcn_sched_barrier(0);
    __builtin_amdgcn_s_barrier();      // all waves done reading cb -> reusable
    cur ^= 1;
  }

  // epilogue: 32x32 C/D layout col=l&31, row=(reg&3)+8*(reg>>2)+4*(l>>5) -> bf16
  unsigned short* Pz = P + (size_t)kz * M * Nc;
#pragma unroll
  for (int i = 0; i < 2; ++i) {
#pragma unroll
    for (int j = 0; j < 2; ++j) {
      int colb = n0 + wc + j * 32 + l31;
#pragma unroll
      for (int r = 0; r < 16; ++r) {
        int row = m0 + wr + i * 32 + (r & 3) + 8 * (r >> 2) + 4 * h;
        Pz[(size_t)row * Nc + colb] = f2bf(acc[i][j][r]);
      }
    }
  }
}

// ---- split-K reduce (bf16 partials) + 1/WSC + bias + ReLU -> fp8 out ----
template <int S>
__global__ void reduce_fp8k(const unsigned short* __restrict__ P, const float* __restrict__ bias,
                            unsigned int* __restrict__ outp, long MN4, int nc4) {
  long i = (long)blockIdx.x * blockDim.x + threadIdx.x;
  long stride = (long)gridDim.x * blockDim.x;
  const ushort4* P4 = (const ushort4*)P;
  const float4* B4 = (const float4*)bias;
  for (; i < MN4; i += stride) {
    float vx = 0, vy = 0, vz = 0, vw = 0;
#pragma unroll
    for (int s = 0; s < S; ++s) {
      ushort4 u = P4[s * MN4 + i];
      vx += bf2f(u.x); vy += bf2f(u.y); vz += bf2f(u.z); vw += bf2f(u.w);
    }
    float4 b = B4[i % nc4];
    vx = fmaxf(vx * (1.0f / WSC) + b.x, 0.0f);
    vy = fmaxf(vy * (1.0f / WSC) + b.y, 0.0f);
    vz = fmaxf(vz * (1.0f / WSC) + b.z, 0.0f);
    vw = fmaxf(vw * (1.0f / WSC) + b.w, 0.0f);
    unsigned int r = (unsigned int)__builtin_amdgcn_cvt_pk_fp8_f32(vx, vy, 0, false);
    r = (unsigned int)__builtin_amdgcn_cvt_pk_fp8_f32(vz, vw, (int)r, true);
    outp[i] = r;
  }
}

// ---- per-row loss, reading GEMM3's 4 bf16 split-K slices + bias directly ----
__global__ void loss_row(const unsigned short* __restrict__ P, const float* __restrict__ bh,
                         const int* __restrict__ labels, const float* __restrict__ tgts,
                         float* __restrict__ nll_v, float* __restrict__ vc_v,
                         float* __restrict__ sl1_v) {
  int r = blockIdx.x;
  int l = threadIdx.x;
  const size_t SL = (size_t)RT * NH;
  const unsigned short* p0 = P + (size_t)r * NH;
#define COLV(c) ((bf2f(p0[(c)]) + bf2f(p0[SL + (c)]) + bf2f(p0[2 * SL + (c)]) + \
                  bf2f(p0[3 * SL + (c)])) * (1.0f / WSC) + bh[(c)])
  float v1 = COLV(l);
  float v2 = (l < CC - 64) ? COLV(64 + l) : -3.4e38f;
  float m = fmaxf(v1, v2);
#pragma unroll
  for (int o = 32; o; o >>= 1) m = fmaxf(m, __shfl_xor(m, o));
  float e = __expf(v1 - m) + ((l < CC - 64) ? __expf(v2 - m) : 0.0f);
#pragma unroll
  for (int o = 32; o; o >>= 1) e += __shfl_xor(e, o);
  if (l == 0) {
    float lse = m + __logf(e);
    int lab = labels[r];
    int sl = lab < 0 ? 0 : (lab > CC - 1 ? CC - 1 : lab);
    float valid = (lab >= 0) ? 1.0f : 0.0f;
    nll_v[r] = (lse - COLV(sl)) * valid;
    vc_v[r] = valid;
    float s = 0.0f;
#pragma unroll
    for (int d = 0; d < 4; ++d) {
      float pd = COLV(CC + sl * 4 + d);
      float ad = fabsf(pd - tgts[r * 4 + d]);
      s += (ad < BETA) ? 0.5f * ad * ad / BETA : ad - 0.5f * BETA;
    }
    sl1_v[r] = (lab > 0) ? s : 0.0f;
  }
#undef COLV
}

// ---- deterministic final reduce ----
__global__ void reduce_final(const float* __restrict__ nll_v, const float* __restrict__ vc_v,
                             const float* __restrict__ sl1_v, float* __restrict__ out) {
  __shared__ float s1[256], s2[256], s3[256];
  int t = threadIdx.x;
  float a = 0, b = 0, c = 0;
  for (int i = t; i < RT; i += 256) { a += nll_v[i]; b += vc_v[i]; c += sl1_v[i]; }
  s1[t] = a; s2[t] = b; s3[t] = c;
  __syncthreads();
  for (int o = 128; o; o >>= 1) {
    if (t < o) { s1[t] += s1[t + o]; s2[t] += s2[t + o]; s3[t] += s3[t + o]; }
    __syncthreads();
  }
  if (t == 0) {
    out[0] = s1[0] / fmaxf(s2[0], 1.0f);
    out[1] = s3[0] / (float)RT;
  }
}

extern "C" void kernel_launch(void* const* d_in, const int* in_sizes, int n_in,
                              void* d_out, int out_size, void* d_ws, size_t ws_size,
                              hipStream_t stream) {
  const float* proposals = (const float*)d_in[0];
  const float* gt_boxes  = (const float*)d_in[1];
  const float* features  = (const float*)d_in[2];
  const float* W1   = (const float*)d_in[3];
  const float* b1   = (const float*)d_in[4];
  const float* W2   = (const float*)d_in[5];
  const float* b2   = (const float*)d_in[6];
  const float* Wcls = (const float*)d_in[7];
  const float* bcls = (const float*)d_in[8];
  const float* Wbox = (const float*)d_in[9];
  const float* bbox = (const float*)d_in[10];
  const int* gt_labels = (const int*)d_in[11];
  float* out = (float*)d_out;

  char* ws = (char*)d_ws;
  unsigned char* W1t = (unsigned char*)(ws + O_W1T);
  unsigned char* W2t = (unsigned char*)(ws + O_W2T);
  unsigned char* Wh  = (unsigned char*)(ws + O_WH);
  float* bh          = (float*)(ws + O_BH);
  unsigned char* x1  = (unsigned char*)(ws + O_X1);
  unsigned char* x2  = (unsigned char*)(ws + O_X2);
  int* labels        = (int*)(ws + O_LAB);
  float* tgts        = (float*)(ws + O_TGT);
  float* nll_v       = (float*)(ws + O_NLL);
  float* vc_v        = (float*)(ws + O_VC);
  float* sl1_v       = (float*)(ws + O_SL1);
  unsigned short* part = (unsigned short*)(ws + O_PART);
  unsigned char* feat8 = (unsigned char*)(ws + O_F8);

  // 1. prep: feature fp8 convert + weight transpose-convert(x64) + head + matcher
  prep<<<NB_PREP, 256, 0, stream>>>(features, (unsigned int*)feat8, W1, W2, Wcls, Wbox,
                                    bcls, bbox, proposals, gt_boxes, gt_labels,
                                    W1t, W2t, Wh, bh, labels, tgts);

  // 2. GEMM1: split-4, pairs=(y,kz)=132, 8 n-blocks -> grid 8*8*17=1088
  gemm_f8<<<1088, 256, 0, stream>>>(feat8, W1t, part, RT, REPD, FEATD, FEATD / 4,
                                    8, 33, 132);
  reduce_fp8k<4><<<2048, 256, 0, stream>>>(part, b1, (unsigned int*)x1,
                                           (long)RT * REPD / 4, REPD / 4);

  // 3. GEMM2: split-2, pairs=66 -> grid 8*8*9=576
  gemm_f8<<<576, 256, 0, stream>>>(x1, W2t, part, RT, REPD, REPD, REPD / 2,
                                   8, 33, 66);
  reduce_fp8k<2><<<2048, 256, 0, stream>>>(part, b2, (unsigned int*)x2,
                                           (long)RT * REPD / 4, REPD / 4);

  // 4. GEMM3: split-4, Nc=512 (4 n-blocks), pairs=132 -> grid 8*4*17=544
  gemm_f8<<<544, 256, 0, stream>>>(x2, Wh, part, RT, NH, REPD, REPD / 4,
                                   4, 33, 132);

  // 5. losses (loss_row folds GEMM3's 4-slice reduce + bias + 1/WSC)
  loss_row<<<RT, 64, 0, stream>>>(part, bh, labels, tgts, nll_v, vc_v, sl1_v);
  reduce_final<<<1, 256, 0, stream>>>(nll_v, vc_v, sl1_v, out);
}